// Round 10
// baseline (935.864 us; speedup 1.0000x reference)
//
#include <hip/hip_runtime.h>
#include <hip/hip_bf16.h>
#include <math.h>

#define NN   50000
#define EE   400000
#define NINP 256
#define HH   4
#define DD   32
#define HIDD 128
#define TNN  4
#define TEE  6
#define LLL  2
#define NOUTT 16
#define NB   196   // (NN+255)/256 scan blocks

// RULE: every LDS array row stride must be a multiple of 4 fp32 / 8 bf16
// elements so vector b128 accesses stay 16B-aligned (2 crashed rounds).
// RULE: every LDS staging loop must cover rows*cols/threads slots (round 6).
// RULE (round 9): weights that fit in L2 should be MFMA-fed from GLOBAL, not
// LDS — B-fragment LDS reads were 8/9 of LDS traffic and bank-conflict bound.

typedef __attribute__((ext_vector_type(8))) short bf16x8;
typedef __attribute__((ext_vector_type(4))) float f32x4;

__device__ __forceinline__ float bf_lo(unsigned u) { return __uint_as_float(u << 16); }
__device__ __forceinline__ float bf_hi(unsigned u) { return __uint_as_float(u & 0xFFFF0000u); }
__device__ __forceinline__ unsigned f2bf(float f) {
    unsigned u = __float_as_uint(f);
    u += 0x7FFFu + ((u >> 16) & 1u);
    return (u >> 16);
}

// ---------------- workspace init ----------------
__global__ void k_init(int* __restrict__ deg, int* __restrict__ cur, int* __restrict__ ncnt,
                       int* __restrict__ ncur, int* __restrict__ nperm) {
    int i = blockIdx.x * 256 + threadIdx.x;
    if (i < NN) { deg[i] = 0; cur[i] = 0; }
    if (i < 16) { ncnt[i] = 0; ncur[i] = 0; }
    if (i < NN + 512) nperm[i] = -1;
}

// ---------------- CSR / sort build ----------------
__global__ void k_count_edges(const int* __restrict__ dst, int* __restrict__ deg) {
    int e = blockIdx.x * 256 + threadIdx.x;
    if (e < EE) atomicAdd(&deg[dst[e]], 1);
}
__global__ void k_count_types(const int* __restrict__ ntype, int* __restrict__ ncnt) {
    int n = blockIdx.x * 256 + threadIdx.x;
    int lane = threadIdx.x & 63;
    int t = (n < NN) ? ntype[n] : -1;
#pragma unroll
    for (int tt = 0; tt < TNN; tt++) {
        unsigned long long mask = __ballot(t == tt);
        if (mask && lane == (__ffsll((unsigned long long)mask) - 1))
            atomicAdd(&ncnt[tt], __popcll(mask));
    }
}
// 3-pass scan
__global__ void k_scan1(const int* __restrict__ deg, int* __restrict__ bsum) {
    int i = blockIdx.x * 256 + threadIdx.x;
    int lane = threadIdx.x & 63, wv = threadIdx.x >> 6;
    __shared__ int ws[4];
    int x = (i < NN) ? deg[i] : 0;
#pragma unroll
    for (int off = 1; off < 64; off <<= 1) x += __shfl_xor(x, off);
    if (lane == 0) ws[wv] = x;
    __syncthreads();
    if (threadIdx.x == 0) bsum[blockIdx.x] = ws[0] + ws[1] + ws[2] + ws[3];
}
__global__ void k_scan2(const int* __restrict__ bsum, int* __restrict__ bpre,
                        const int* __restrict__ ncnt, int* __restrict__ meta) {
    __shared__ int ws[4];
    int tid = threadIdx.x, lane = tid & 63, wv = tid >> 6;
    int v = (tid < NB) ? bsum[tid] : 0;
    int x = v;
#pragma unroll
    for (int off = 1; off < 64; off <<= 1) {
        int y = __shfl_up(x, off);
        if (lane >= off) x += y;
    }
    if (lane == 63) ws[wv] = x;
    __syncthreads();
    if (tid == 0) { int a = 0; for (int w = 0; w < 4; w++) { int s = ws[w]; ws[w] = a; a += s; } }
    __syncthreads();
    if (tid < NB) bpre[tid] = x - v + ws[wv];
    if (tid == 0) {
        int acc = 0;
        meta[0] = 0;
        for (int t = 0; t < TNN; t++) { acc += ((ncnt[t] + 63) >> 6) << 6; meta[t + 1] = acc; }
    }
}
__global__ void k_scan3(const int* __restrict__ deg, const int* __restrict__ bpre,
                        int* __restrict__ offs) {
    int b = blockIdx.x;
    int tid = threadIdx.x, lane = tid & 63, wv = tid >> 6;
    int i = b * 256 + tid;
    __shared__ int ws[4];
    int v = (i < NN) ? deg[i] : 0;
    int x = v;
#pragma unroll
    for (int off = 1; off < 64; off <<= 1) {
        int y = __shfl_up(x, off);
        if (lane >= off) x += y;
    }
    if (lane == 63) ws[wv] = x;
    __syncthreads();
    if (tid == 0) { int a = 0; for (int w = 0; w < 4; w++) { int s = ws[w]; ws[w] = a; a += s; } }
    __syncthreads();
    if (i < NN) offs[i + 1] = x + ws[wv] + bpre[b];
    if (b == 0 && tid == 0) offs[0] = 0;
}
// writes packed (src<<3)|etype per CSR slot (one dependent-load level removed in k_edge)
__global__ void k_scatter_edges(const int* __restrict__ dst, const int* __restrict__ src,
                                const int* __restrict__ etype, const int* __restrict__ offs,
                                int* __restrict__ cur, unsigned* __restrict__ se) {
    int e = blockIdx.x * 256 + threadIdx.x;
    if (e < EE) {
        int d = dst[e];
        int p = atomicAdd(&cur[d], 1);
        se[offs[d] + p] = ((unsigned)src[e] << 3) | (unsigned)etype[e];
    }
}
__global__ void k_scatter_nodes(const int* __restrict__ ntype, const int* __restrict__ meta,
                                int* __restrict__ ncur, int* __restrict__ nperm) {
    int n = blockIdx.x * 256 + threadIdx.x;
    int lane = threadIdx.x & 63;
    int t = (n < NN) ? ntype[n] : -1;
#pragma unroll
    for (int tt = 0; tt < TNN; tt++) {
        unsigned long long mask = __ballot(t == tt);
        if (t == tt) {
            int rank = __popcll(mask & ((1ull << lane) - 1ull));
            int leader = __ffsll((unsigned long long)mask) - 1;
            int b = 0;
            if (rank == 0) b = atomicAdd(&ncur[tt], __popcll(mask));
            b = __shfl(b, leader);
            nperm[meta[tt] + b + rank] = n;
        }
    }
}

// ---------------- weight transpose+convert: W[t][k][n] f32 -> WT[t][n][k] bf16 ----------
__global__ void k_wt(const float* __restrict__ adapt_W, const float* __restrict__ Wk,
                     const float* __restrict__ Wla, unsigned short* __restrict__ adaptT,
                     unsigned short* __restrict__ Wf, unsigned short* __restrict__ WlaT) {
    __shared__ float Ts[64][68];  // 272B row stride
    int b = blockIdx.x, tid = threadIdx.x;
    const float* src;
    unsigned short* dst;
    int K, kt, nt;
    if (b < 32) {
        int t = b >> 3, tile = b & 7;
        K = 256; kt = tile >> 1; nt = tile & 1;
        src = adapt_W + (size_t)t * 256 * 128;
        dst = adaptT + (size_t)t * 128 * 256;
    } else if (b < 64) {
        int b2 = b - 32, l = b2 >> 4, r = b2 & 15, t = r >> 2, tile = r & 3;
        K = 128; kt = tile >> 1; nt = tile & 1;
        src = Wk + (size_t)(l * 4 + t) * 16384;
        dst = Wf + (size_t)(l * TNN + t) * 1664 * 128;  // fused rows 0..127
    } else {
        int b2 = b - 64, l = b2 >> 4, r = b2 & 15, t = r >> 2, tile = r & 3;
        K = 128; kt = tile >> 1; nt = tile & 1;
        src = Wla + (size_t)(l * 4 + t) * 16384;
        dst = WlaT + (size_t)(l * 4 + t) * 16384;
    }
    int k0 = kt * 64, n0 = nt * 64;
#pragma unroll
    for (int it = 0; it < 4; it++) {  // 64x16 slots
        int idx = tid + it * 256;
        int row = idx >> 4, c4 = (idx & 15) * 4;
        *(float4*)(&Ts[row][c4]) = *(const float4*)(src + (size_t)(k0 + row) * 128 + n0 + c4);
    }
    __syncthreads();
#pragma unroll
    for (int it = 0; it < 2; it++) {  // 64x8 slots
        int idx = tid + it * 256;
        int nn = idx >> 3, sg = (idx & 7) * 8;
        uint4 pk;
        pk.x = f2bf(Ts[sg + 0][nn]) | (f2bf(Ts[sg + 1][nn]) << 16);
        pk.y = f2bf(Ts[sg + 2][nn]) | (f2bf(Ts[sg + 3][nn]) << 16);
        pk.z = f2bf(Ts[sg + 4][nn]) | (f2bf(Ts[sg + 5][nn]) << 16);
        pk.w = f2bf(Ts[sg + 6][nn]) | (f2bf(Ts[sg + 7][nn]) << 16);
        *(uint4*)(dst + (size_t)(n0 + nn) * K + k0 + sg) = pk;
    }
}

// ---------------- combined weights into fused buffer ----------------
__global__ void k_comb(const float* __restrict__ Wq, const float* __restrict__ Wa,
                       const float* __restrict__ Wv, const float* __restrict__ Wm,
                       const float* __restrict__ pri, unsigned short* __restrict__ Wf) {
    __shared__ float Ls[128][36];
    __shared__ float Ss[32][36];
    __shared__ unsigned short Ot[32][136];
    int b = blockIdx.x, tid = threadIdx.x;
    int mode = b / 192;
    int rem = b % 192;
    int l = rem / 96;
    int rem2 = rem % 96;
    int t = rem2 / 24;
    int ht = rem2 % 24;
    int hh = ht / 6, te = ht % 6;
    const float* L = (mode == 0 ? Wq : Wv) + ((size_t)(l * TNN + t)) * 16384;
    const float* S = (mode == 0 ? Wa : Wm) + ((size_t)((l * HH + hh) * TEE + te)) * 1024;
    float ps = (mode == 0) ? pri[(l * HH + hh) * TEE + te] * 0.17677669529663687f : 1.0f;
#pragma unroll
    for (int it = 0; it < 4; it++) {  // 128x8 slots = 1024
        int idx = tid + it * 256;
        int kk = idx >> 3, c4 = (idx & 7) * 4;
        *(float4*)(&Ls[kk][c4]) = *(const float4*)(L + (size_t)kk * 128 + hh * 32 + c4);
    }
    {
        int r = tid >> 3, c4 = (tid & 7) * 4;
        *(float4*)(&Ss[r][c4]) = *(const float4*)(S + r * 32 + c4);
    }
    __syncthreads();
    int k = tid >> 1, half = tid & 1;
#pragma unroll
    for (int jj = 0; jj < 16; jj++) {
        int j = half * 16 + jj;
        float s = 0.f;
        if (mode == 0) {
#pragma unroll
            for (int o = 0; o < 32; o++) s += Ls[k][o] * Ss[j][o];
        } else {
#pragma unroll
            for (int d = 0; d < 32; d++) s += Ls[k][d] * Ss[d][j];
        }
        Ot[j][k] = (unsigned short)f2bf(s * ps);
    }
    __syncthreads();
    unsigned short* dst = Wf + ((size_t)(l * TNN + t) * 1664 + (mode == 0 ? 128 : 896)) * 128;
#pragma unroll
    for (int it = 0; it < 2; it++) {  // 32x16 slots
        int idx = tid + it * 256;
        int j = idx >> 4, sg = (idx & 15) * 8;
        uint4 pk = *(const uint4*)(&Ot[j][sg]);
        int jg = (hh * 6 + te) * 32 + j;
        *(uint4*)(dst + (size_t)jg * 128 + sg) = pk;
    }
}

// ---------------- MFMA typed GEMM: B fed from global (L2-resident weights) ----------
// Y[node] = A[node] @ WT[type]^T
// AF32: A fp32 (converted during staging). EPI: 0 none, 1 bias+gelu,
// 2 fused skip-blend+LayerNorm (reads/writes hres fp32, writes hbout bf16).
// OMODE (EPI<2): 0 fp32 out, 1 bf16 out, 2 both
template <int K, int NCB, int EPI, int OMODE, int AF32>
__launch_bounds__(256) __global__
void k_gemm(const void* __restrict__ Av, const unsigned short* __restrict__ WT,
            const float* __restrict__ bias, float* __restrict__ Yf,
            unsigned short* __restrict__ Yb, const int* __restrict__ nperm,
            const int* __restrict__ meta, const float* __restrict__ skipv,
            const float* __restrict__ gamma, const float* __restrict__ beta,
            float* __restrict__ hres, unsigned short* __restrict__ hbout) {
    constexpr int CBS = (EPI == 2) ? 132 : 68;  // Cb stride (floats), both 16B multiples
    __shared__ __align__(16) unsigned short Ab[64 * 136];  // 272B stride
    __shared__ __align__(16) float Cb[64 * CBS];
    const int WIDTH = NCB * 128;
    int row0 = blockIdx.x * 64;
    if (row0 >= meta[4]) return;
    int t = 0;
    while (t < 3 && row0 >= meta[t + 1]) t++;
    const unsigned short* WTt = WT + (size_t)t * WIDTH * K;
    int tid = threadIdx.x;
    int lane = tid & 63, w = tid >> 6;
    int m = lane & 15, q = lane >> 4;

#pragma unroll 1
    for (int cb = 0; cb < NCB; cb++) {
        f32x4 acc[8];
#pragma unroll
        for (int g = 0; g < 8; g++) acc[g] = (f32x4){0.f, 0.f, 0.f, 0.f};
#pragma unroll
        for (int kc = 0; kc < K / 128; kc++) {
            if (NCB == 1 || cb == 0) {
                __syncthreads();  // prior reads of Ab done (K=256 restage / epilogue)
                if (AF32) {
                    const float* A = (const float*)Av;
#pragma unroll
                    for (int it = 0; it < 8; it++) {  // 64 rows x 32 slots x 4 floats
                        int idx = tid + it * 256;
                        int r = idx >> 5, c4 = (idx & 31) * 4;
                        int node = nperm[row0 + r];
                        float4 v = make_float4(0.f, 0.f, 0.f, 0.f);
                        if (node >= 0)
                            v = *(const float4*)(A + (size_t)node * K + kc * 128 + c4);
                        uint2 pk;
                        pk.x = f2bf(v.x) | (f2bf(v.y) << 16);
                        pk.y = f2bf(v.z) | (f2bf(v.w) << 16);
                        *(uint2*)(Ab + r * 136 + c4) = pk;
                    }
                } else {
                    const unsigned short* A = (const unsigned short*)Av;
#pragma unroll
                    for (int it = 0; it < 4; it++) {  // 64 rows x 16 slots x 8 bf16
                        int idx = tid + it * 256;
                        int r = idx >> 4, sg = idx & 15;
                        int node = nperm[row0 + r];
                        uint4 v = make_uint4(0, 0, 0, 0);
                        if (node >= 0)
                            v = *(const uint4*)(A + (size_t)node * K + kc * 128 + sg * 8);
                        *(uint4*)(Ab + r * 136 + sg * 8) = v;
                    }
                }
                __syncthreads();
            }
            // B fragments straight from global (L2-resident); lane (m,q) reads 16B
            // of row g*16+m -> per wave 16 full 64B lines, no LDS round-trip.
            const unsigned short* Bbase = WTt + (size_t)cb * 128 * K + (size_t)kc * 128;
#pragma unroll
            for (int k0 = 0; k0 < 128; k0 += 32) {
                bf16x8 a = *(const bf16x8*)(Ab + (w * 16 + m) * 136 + k0 + q * 8);
#pragma unroll
                for (int g = 0; g < 8; g++) {
                    bf16x8 bb = *(const bf16x8*)(Bbase + (size_t)(g * 16 + m) * K + k0 + q * 8);
                    acc[g] = __builtin_amdgcn_mfma_f32_16x16x32_bf16(a, bb, acc[g], 0, 0, 0);
                }
            }
        }
        if (EPI == 2) {
            __syncthreads();  // prior Cb readers done
#pragma unroll
            for (int g = 0; g < 8; g++)
#pragma unroll
                for (int r = 0; r < 4; r++)
                    Cb[(w * 16 + q * 4 + r) * 132 + g * 16 + m] = acc[g][r];
            __syncthreads();
            // fused skip-blend + LayerNorm; tile type t uniform -> alpha scalar
            float alpha = 1.0f / (1.0f + __expf(-skipv[t]));
            int off = lane * 2;
            float2 g2 = *(const float2*)(gamma + off);
            float2 b2 = *(const float2*)(beta + off);
#pragma unroll 1
            for (int it = 0; it < 16; it++) {
                int row = w * 16 + it;
                int node = nperm[row0 + row];
                if (node < 0) continue;
                float ax = Cb[row * 132 + off];
                float ay = Cb[row * 132 + off + 1];
                float2 h2 = *(const float2*)(hres + (size_t)node * 128 + off);
                float ox = ax * alpha + h2.x * (1.f - alpha);
                float oy = ay * alpha + h2.y * (1.f - alpha);
                float s = ox + oy;
#pragma unroll
                for (int mm = 1; mm < 64; mm <<= 1) s += __shfl_xor(s, mm);
                float mu = s * (1.0f / 128.0f);
                float dx = ox - mu, dy = oy - mu;
                float v2 = dx * dx + dy * dy;
#pragma unroll
                for (int mm = 1; mm < 64; mm <<= 1) v2 += __shfl_xor(v2, mm);
                float rs = rsqrtf(v2 * (1.0f / 128.0f) + 1e-5f);
                float vx = dx * rs * g2.x + b2.x;
                float vy = dy * rs * g2.y + b2.y;
                *(float2*)(hres + (size_t)node * 128 + off) = make_float2(vx, vy);
                *(unsigned*)(hbout + (size_t)node * 128 + off) = f2bf(vx) | (f2bf(vy) << 16);
            }
        } else {
            // two 64-col halves through a half-width Cb (smaller LDS -> 4 blocks/CU)
#pragma unroll 1
            for (int hf = 0; hf < 2; hf++) {
                __syncthreads();  // prior Cb readers done
#pragma unroll
                for (int g = 0; g < 4; g++)
#pragma unroll
                    for (int r = 0; r < 4; r++)
                        Cb[(w * 16 + q * 4 + r) * 68 + g * 16 + m] = acc[hf * 4 + g][r];
                __syncthreads();
#pragma unroll
                for (int it = 0; it < 4; it++) {  // 64 rows x 16 slots
                    int idx = tid + it * 256;
                    int row = idx >> 4, c4 = (idx & 15) * 4;
                    int node = nperm[row0 + row];
                    if (node < 0) continue;
                    float4 v = *(const float4*)(Cb + row * 68 + c4);
                    if (EPI == 1) {
                        float4 bv = *(const float4*)(bias + t * 128 + hf * 64 + c4);
                        v.x += bv.x; v.y += bv.y; v.z += bv.z; v.w += bv.w;
                        const float is2 = 0.70710678118654752f;
                        v.x = 0.5f * v.x * (1.f + erff(v.x * is2));
                        v.y = 0.5f * v.y * (1.f + erff(v.y * is2));
                        v.z = 0.5f * v.z * (1.f + erff(v.z * is2));
                        v.w = 0.5f * v.w * (1.f + erff(v.w * is2));
                    }
                    int col = cb * 128 + hf * 64 + c4;
                    if (OMODE == 0 || OMODE == 2)
                        *(float4*)(Yf + (size_t)node * WIDTH + col) = v;
                    if (OMODE == 1 || OMODE == 2) {
                        uint2 pk;
                        pk.x = f2bf(v.x) | (f2bf(v.y) << 16);
                        pk.y = f2bf(v.z) | (f2bf(v.w) << 16);
                        *(uint2*)(Yb + (size_t)node * WIDTH + col) = pk;
                    }
                }
            }
        }
    }
}

// ---------------- fused edge pass, 4-edge unrolled, packed (src,etype) ----------------
// kqv[n][1664]: cols 0..127 = k, 128..895 = qhat, 896..1663 = vhat
__global__ void k_edge(const unsigned short* __restrict__ kqv,
                       const int* __restrict__ offs, const unsigned* __restrict__ se,
                       unsigned short* __restrict__ aggb) {
    int lane = threadIdx.x & 63;
    int wid = blockIdx.x * (blockDim.x >> 6) + (threadIdx.x >> 6);
    int nw = gridDim.x * (blockDim.x >> 6);
    int h = lane >> 4;
    int i2 = (lane & 15) * 2;
    int hoff = h * 32 + i2;
    for (int n = wid; n < NN; n += nw) {
        int e0 = offs[n], e1 = offs[n + 1];
        float ax = 0.f, ay = 0.f, den = 0.f;
        const unsigned short* qrow = kqv + (size_t)n * 1664 + 128;
        int s[4], t[4];
#pragma unroll
        for (int u = 0; u < 4; u++) {
            s[u] = 0; t[u] = 0;
            if (e0 + u < e1) { unsigned p0 = se[e0 + u]; s[u] = p0 >> 3; t[u] = p0 & 7; }
        }
        int j = e0;
        while (j + 3 < e1) {
            unsigned ku[4], qu[4], vu[4];
#pragma unroll
            for (int u = 0; u < 4; u++) {
                int to = (h * 6 + t[u]) * 32 + i2;
                ku[u] = *(const unsigned*)(kqv + (size_t)s[u] * 1664 + hoff);
                qu[u] = *(const unsigned*)(qrow + to);
                vu[u] = *(const unsigned*)(kqv + (size_t)s[u] * 1664 + 896 + to);
            }
            int jn = j + 4;
#pragma unroll
            for (int u = 0; u < 4; u++)
                if (jn + u < e1) { unsigned p0 = se[jn + u]; s[u] = p0 >> 3; t[u] = p0 & 7; }
            float p[4];
#pragma unroll
            for (int u = 0; u < 4; u++)
                p[u] = bf_lo(ku[u]) * bf_lo(qu[u]) + bf_hi(ku[u]) * bf_hi(qu[u]);
#pragma unroll
            for (int mm = 1; mm < 16; mm <<= 1) {
#pragma unroll
                for (int u = 0; u < 4; u++) p[u] += __shfl_xor(p[u], mm);
            }
#pragma unroll
            for (int u = 0; u < 4; u++) {
                float ex = __expf(p[u]);
                den += ex;
                ax += ex * bf_lo(vu[u]);
                ay += ex * bf_hi(vu[u]);
            }
            j = jn;
        }
        for (int u = 0; j < e1; j++, u++) {  // tail 0..3 edges
            int to = (h * 6 + t[u]) * 32 + i2;
            unsigned ku = *(const unsigned*)(kqv + (size_t)s[u] * 1664 + hoff);
            unsigned qu = *(const unsigned*)(qrow + to);
            unsigned vu = *(const unsigned*)(kqv + (size_t)s[u] * 1664 + 896 + to);
            float p0 = bf_lo(ku) * bf_lo(qu) + bf_hi(ku) * bf_hi(qu);
            p0 += __shfl_xor(p0, 1);
            p0 += __shfl_xor(p0, 2);
            p0 += __shfl_xor(p0, 4);
            p0 += __shfl_xor(p0, 8);
            float ex = __expf(p0);
            den += ex;
            ax += ex * bf_lo(vu);
            ay += ex * bf_hi(vu);
        }
        float r = (den > 0.f) ? (1.0f / den) : 0.f;
        unsigned pk = f2bf(ax * r) | (f2bf(ay * r) << 16);
        *(unsigned*)(aggb + (size_t)n * 128 + hoff) = pk;
    }
}

// ---------------- output projection (reads bf16 hb) ----------------
__global__ void k_out(const unsigned short* __restrict__ hb, const float* __restrict__ Wo,
                      const float* __restrict__ bo, float* __restrict__ out) {
    __shared__ float Ws[128 * 16];
    int tid = threadIdx.x;
#pragma unroll
    for (int it = 0; it < 2; it++) {
        int idx = (tid + it * 256) * 4;
        *(float4*)(&Ws[idx]) = *(const float4*)(Wo + idx);
    }
    __syncthreads();
    int nl = tid >> 4;
    int o = tid & 15;
    int n = blockIdx.x * 16 + nl;
    float acc = bo[o];
    const unsigned short* hr = hb + (size_t)n * 128;
#pragma unroll
    for (int kk = 0; kk < 128; kk += 8) {
        uint4 hv = *(const uint4*)(hr + kk);
        acc += bf_lo(hv.x) * Ws[(kk + 0) * 16 + o] + bf_hi(hv.x) * Ws[(kk + 1) * 16 + o] +
               bf_lo(hv.y) * Ws[(kk + 2) * 16 + o] + bf_hi(hv.y) * Ws[(kk + 3) * 16 + o] +
               bf_lo(hv.z) * Ws[(kk + 4) * 16 + o] + bf_hi(hv.z) * Ws[(kk + 5) * 16 + o] +
               bf_lo(hv.w) * Ws[(kk + 6) * 16 + o] + bf_hi(hv.w) * Ws[(kk + 7) * 16 + o];
    }
    out[(size_t)n * 16 + o] = acc;
}

extern "C" void kernel_launch(void* const* d_in, const int* in_sizes, int n_in,
                              void* d_out, int out_size, void* d_ws, size_t ws_size,
                              hipStream_t stream) {
    const float* x       = (const float*)d_in[0];
    const float* adapt_W = (const float*)d_in[1];
    const float* adapt_b = (const float*)d_in[2];
    const float* Wk      = (const float*)d_in[3];
    const float* Wq      = (const float*)d_in[4];
    const float* Wv      = (const float*)d_in[5];
    const float* pri     = (const float*)d_in[6];
    const float* Wa      = (const float*)d_in[7];
    const float* Wm      = (const float*)d_in[8];
    const float* Wla     = (const float*)d_in[9];
    const float* skip    = (const float*)d_in[10];
    const float* gamma   = (const float*)d_in[11];
    const float* beta    = (const float*)d_in[12];
    const float* out_W   = (const float*)d_in[13];
    const float* out_b   = (const float*)d_in[14];
    const int* ntype     = (const int*)d_in[15];
    const int* etype     = (const int*)d_in[16];
    const int* src       = (const int*)d_in[17];
    const int* dst       = (const int*)d_in[18];
    float* out = (float*)d_out;

    char* p = (char*)d_ws;
    auto al = [](size_t v) { return (v + 255) & ~(size_t)255; };
    float* h  = (float*)p;          p += al((size_t)NN * 128 * 4);
    unsigned short* hb   = (unsigned short*)p; p += al((size_t)NN * 128 * 2);
    unsigned short* aggb = (unsigned short*)p; p += al((size_t)NN * 128 * 2);
    unsigned short* kqvb = (unsigned short*)p; p += al((size_t)NN * 1664 * 2);
    unsigned short* adaptT = (unsigned short*)p; p += al((size_t)TNN * 128 * 256 * 2);
    unsigned short* WlaT   = (unsigned short*)p; p += al((size_t)LLL * TNN * 16384 * 2);
    unsigned short* Wf     = (unsigned short*)p; p += al((size_t)LLL * TNN * 1664 * 128 * 2);
    int* deg   = (int*)p; p += al((size_t)NN * 4);
    int* offs  = (int*)p; p += al((size_t)(NN + 1) * 4);
    int* cur   = (int*)p; p += al((size_t)NN * 4);
    unsigned* se = (unsigned*)p; p += al((size_t)EE * 4);
    int* nperm = (int*)p; p += al((size_t)(NN + 512) * 4);
    int* bsum  = (int*)p; p += al(256 * 4);
    int* bpre  = (int*)p; p += al(256 * 4);
    int* ncnt  = (int*)p; p += al(64);
    int* ncur  = (int*)p; p += al(64);
    int* meta  = (int*)p; p += al(64);

    k_init<<<(NN + 512 + 255) / 256, 256, 0, stream>>>(deg, cur, ncnt, ncur, nperm);
    k_count_edges<<<(EE + 255) / 256, 256, 0, stream>>>(dst, deg);
    k_count_types<<<(NN + 255) / 256, 256, 0, stream>>>(ntype, ncnt);
    k_scan1<<<NB, 256, 0, stream>>>(deg, bsum);
    k_scan2<<<1, 256, 0, stream>>>(bsum, bpre, ncnt, meta);
    k_scan3<<<NB, 256, 0, stream>>>(deg, bpre, offs);
    k_scatter_edges<<<(EE + 255) / 256, 256, 0, stream>>>(dst, src, etype, offs, cur, se);
    k_scatter_nodes<<<(NN + 255) / 256, 256, 0, stream>>>(ntype, meta, ncur, nperm);

    k_wt<<<96, 256, 0, stream>>>(adapt_W, Wk, Wla, adaptT, Wf, WlaT);
    k_comb<<<384, 256, 0, stream>>>(Wq, Wa, Wv, Wm, pri, Wf);

    const int TILES = NN / 64 + TNN + 1;

    // adapt: h = gelu(x @ adaptT + b) with on-the-fly fp32->bf16 A-staging
    k_gemm<256, 1, 1, 2, 1><<<TILES, 256, 0, stream>>>(
        x, adaptT, adapt_b, h, hb, nperm, meta, nullptr, nullptr, nullptr, nullptr, nullptr);

    for (int l = 0; l < LLL; l++) {
        // fused K|Q|V: kqv[n][1664] in one MFMA GEMM (B from global/L2)
        k_gemm<128, 13, 0, 1, 0><<<TILES, 256, 0, stream>>>(
            hb, Wf + (size_t)l * TNN * 1664 * 128, nullptr, nullptr, kqvb, nperm, meta,
            nullptr, nullptr, nullptr, nullptr, nullptr);

        k_edge<<<4096, 256, 0, stream>>>(kqvb, offs, se, aggb);

        // Wla GEMM + fused skip-blend + LayerNorm (updates h fp32 and hb bf16)
        k_gemm<128, 1, 2, 0, 0><<<TILES, 256, 0, stream>>>(
            aggb, WlaT + (size_t)l * TNN * 16384, nullptr, nullptr, nullptr, nperm, meta,
            skip + (size_t)l * TNN, gamma + (size_t)l * HIDD, beta + (size_t)l * HIDD,
            h, hb);
    }

    k_out<<<NN / 16, 256, 0, stream>>>(hb, out_W, out_b, out);
}

// Round 11
// 649.289 us; speedup vs baseline: 1.4414x; 1.4414x over previous
//
#include <hip/hip_runtime.h>
#include <hip/hip_bf16.h>
#include <math.h>

#define NN   50000
#define EE   400000
#define NINP 256
#define HH   4
#define DD   32
#define HIDD 128
#define TNN  4
#define TEE  6
#define LLL  2
#define NOUTT 16
#define NB   196   // (NN+255)/256 scan blocks

// RULE: every LDS array row stride must be a multiple of 4 fp32 / 8 bf16
// elements so vector b128 accesses stay 16B-aligned (2 crashed rounds).
// RULE: every LDS staging loop must cover rows*cols/threads slots (round 6).
// RULE (round 10): do NOT feed MFMA operands straight from global — L2 latency
// stalls the MFMA pipe (86->202us). Reduce LDS pressure by reducing read COUNT
// (column-split wave mapping: 6 reads/8 MFMAs instead of 9).

typedef __attribute__((ext_vector_type(8))) short bf16x8;
typedef __attribute__((ext_vector_type(4))) float f32x4;

__device__ __forceinline__ float bf_lo(unsigned u) { return __uint_as_float(u << 16); }
__device__ __forceinline__ float bf_hi(unsigned u) { return __uint_as_float(u & 0xFFFF0000u); }
__device__ __forceinline__ unsigned f2bf(float f) {
    unsigned u = __float_as_uint(f);
    u += 0x7FFFu + ((u >> 16) & 1u);
    return (u >> 16);
}

// ---------------- workspace init ----------------
__global__ void k_init(int* __restrict__ deg, int* __restrict__ cur, int* __restrict__ ncnt,
                       int* __restrict__ ncur, int* __restrict__ nperm) {
    int i = blockIdx.x * 256 + threadIdx.x;
    if (i < NN) { deg[i] = 0; cur[i] = 0; }
    if (i < 16) { ncnt[i] = 0; ncur[i] = 0; }
    if (i < NN + 512) nperm[i] = -1;
}

// ---------------- CSR / sort build ----------------
__global__ void k_count_edges(const int* __restrict__ dst, int* __restrict__ deg) {
    int e = blockIdx.x * 256 + threadIdx.x;
    if (e < EE) atomicAdd(&deg[dst[e]], 1);
}
__global__ void k_count_types(const int* __restrict__ ntype, int* __restrict__ ncnt) {
    int n = blockIdx.x * 256 + threadIdx.x;
    int lane = threadIdx.x & 63;
    int t = (n < NN) ? ntype[n] : -1;
#pragma unroll
    for (int tt = 0; tt < TNN; tt++) {
        unsigned long long mask = __ballot(t == tt);
        if (mask && lane == (__ffsll((unsigned long long)mask) - 1))
            atomicAdd(&ncnt[tt], __popcll(mask));
    }
}
// 3-pass scan
__global__ void k_scan1(const int* __restrict__ deg, int* __restrict__ bsum) {
    int i = blockIdx.x * 256 + threadIdx.x;
    int lane = threadIdx.x & 63, wv = threadIdx.x >> 6;
    __shared__ int ws[4];
    int x = (i < NN) ? deg[i] : 0;
#pragma unroll
    for (int off = 1; off < 64; off <<= 1) x += __shfl_xor(x, off);
    if (lane == 0) ws[wv] = x;
    __syncthreads();
    if (threadIdx.x == 0) bsum[blockIdx.x] = ws[0] + ws[1] + ws[2] + ws[3];
}
__global__ void k_scan2(const int* __restrict__ bsum, int* __restrict__ bpre,
                        const int* __restrict__ ncnt, int* __restrict__ meta) {
    __shared__ int ws[4];
    int tid = threadIdx.x, lane = tid & 63, wv = tid >> 6;
    int v = (tid < NB) ? bsum[tid] : 0;
    int x = v;
#pragma unroll
    for (int off = 1; off < 64; off <<= 1) {
        int y = __shfl_up(x, off);
        if (lane >= off) x += y;
    }
    if (lane == 63) ws[wv] = x;
    __syncthreads();
    if (tid == 0) { int a = 0; for (int w = 0; w < 4; w++) { int s = ws[w]; ws[w] = a; a += s; } }
    __syncthreads();
    if (tid < NB) bpre[tid] = x - v + ws[wv];
    if (tid == 0) {
        int acc = 0;
        meta[0] = 0;
        for (int t = 0; t < TNN; t++) { acc += ((ncnt[t] + 63) >> 6) << 6; meta[t + 1] = acc; }
    }
}
__global__ void k_scan3(const int* __restrict__ deg, const int* __restrict__ bpre,
                        int* __restrict__ offs) {
    int b = blockIdx.x;
    int tid = threadIdx.x, lane = tid & 63, wv = tid >> 6;
    int i = b * 256 + tid;
    __shared__ int ws[4];
    int v = (i < NN) ? deg[i] : 0;
    int x = v;
#pragma unroll
    for (int off = 1; off < 64; off <<= 1) {
        int y = __shfl_up(x, off);
        if (lane >= off) x += y;
    }
    if (lane == 63) ws[wv] = x;
    __syncthreads();
    if (tid == 0) { int a = 0; for (int w = 0; w < 4; w++) { int s = ws[w]; ws[w] = a; a += s; } }
    __syncthreads();
    if (i < NN) offs[i + 1] = x + ws[wv] + bpre[b];
    if (b == 0 && tid == 0) offs[0] = 0;
}
// writes packed (src<<3)|etype per CSR slot
__global__ void k_scatter_edges(const int* __restrict__ dst, const int* __restrict__ src,
                                const int* __restrict__ etype, const int* __restrict__ offs,
                                int* __restrict__ cur, unsigned* __restrict__ se) {
    int e = blockIdx.x * 256 + threadIdx.x;
    if (e < EE) {
        int d = dst[e];
        int p = atomicAdd(&cur[d], 1);
        se[offs[d] + p] = ((unsigned)src[e] << 3) | (unsigned)etype[e];
    }
}
__global__ void k_scatter_nodes(const int* __restrict__ ntype, const int* __restrict__ meta,
                                int* __restrict__ ncur, int* __restrict__ nperm) {
    int n = blockIdx.x * 256 + threadIdx.x;
    int lane = threadIdx.x & 63;
    int t = (n < NN) ? ntype[n] : -1;
#pragma unroll
    for (int tt = 0; tt < TNN; tt++) {
        unsigned long long mask = __ballot(t == tt);
        if (t == tt) {
            int rank = __popcll(mask & ((1ull << lane) - 1ull));
            int leader = __ffsll((unsigned long long)mask) - 1;
            int b = 0;
            if (rank == 0) b = atomicAdd(&ncur[tt], __popcll(mask));
            b = __shfl(b, leader);
            nperm[meta[tt] + b + rank] = n;
        }
    }
}

// ---------------- weight transpose+convert: W[t][k][n] f32 -> WT[t][n][k] bf16 ----------
__global__ void k_wt(const float* __restrict__ adapt_W, const float* __restrict__ Wk,
                     const float* __restrict__ Wla, unsigned short* __restrict__ adaptT,
                     unsigned short* __restrict__ Wf, unsigned short* __restrict__ WlaT) {
    __shared__ float Ts[64][68];  // 272B row stride
    int b = blockIdx.x, tid = threadIdx.x;
    const float* src;
    unsigned short* dst;
    int K, kt, nt;
    if (b < 32) {
        int t = b >> 3, tile = b & 7;
        K = 256; kt = tile >> 1; nt = tile & 1;
        src = adapt_W + (size_t)t * 256 * 128;
        dst = adaptT + (size_t)t * 128 * 256;
    } else if (b < 64) {
        int b2 = b - 32, l = b2 >> 4, r = b2 & 15, t = r >> 2, tile = r & 3;
        K = 128; kt = tile >> 1; nt = tile & 1;
        src = Wk + (size_t)(l * 4 + t) * 16384;
        dst = Wf + (size_t)(l * TNN + t) * 1664 * 128;  // fused rows 0..127
    } else {
        int b2 = b - 64, l = b2 >> 4, r = b2 & 15, t = r >> 2, tile = r & 3;
        K = 128; kt = tile >> 1; nt = tile & 1;
        src = Wla + (size_t)(l * 4 + t) * 16384;
        dst = WlaT + (size_t)(l * 4 + t) * 16384;
    }
    int k0 = kt * 64, n0 = nt * 64;
#pragma unroll
    for (int it = 0; it < 4; it++) {  // 64x16 slots
        int idx = tid + it * 256;
        int row = idx >> 4, c4 = (idx & 15) * 4;
        *(float4*)(&Ts[row][c4]) = *(const float4*)(src + (size_t)(k0 + row) * 128 + n0 + c4);
    }
    __syncthreads();
#pragma unroll
    for (int it = 0; it < 2; it++) {  // 64x8 slots
        int idx = tid + it * 256;
        int nn = idx >> 3, sg = (idx & 7) * 8;
        uint4 pk;
        pk.x = f2bf(Ts[sg + 0][nn]) | (f2bf(Ts[sg + 1][nn]) << 16);
        pk.y = f2bf(Ts[sg + 2][nn]) | (f2bf(Ts[sg + 3][nn]) << 16);
        pk.z = f2bf(Ts[sg + 4][nn]) | (f2bf(Ts[sg + 5][nn]) << 16);
        pk.w = f2bf(Ts[sg + 6][nn]) | (f2bf(Ts[sg + 7][nn]) << 16);
        *(uint4*)(dst + (size_t)(n0 + nn) * K + k0 + sg) = pk;
    }
}

// ---------------- combined weights into fused buffer ----------------
__global__ void k_comb(const float* __restrict__ Wq, const float* __restrict__ Wa,
                       const float* __restrict__ Wv, const float* __restrict__ Wm,
                       const float* __restrict__ pri, unsigned short* __restrict__ Wf) {
    __shared__ float Ls[128][36];
    __shared__ float Ss[32][36];
    __shared__ unsigned short Ot[32][136];
    int b = blockIdx.x, tid = threadIdx.x;
    int mode = b / 192;
    int rem = b % 192;
    int l = rem / 96;
    int rem2 = rem % 96;
    int t = rem2 / 24;
    int ht = rem2 % 24;
    int hh = ht / 6, te = ht % 6;
    const float* L = (mode == 0 ? Wq : Wv) + ((size_t)(l * TNN + t)) * 16384;
    const float* S = (mode == 0 ? Wa : Wm) + ((size_t)((l * HH + hh) * TEE + te)) * 1024;
    float ps = (mode == 0) ? pri[(l * HH + hh) * TEE + te] * 0.17677669529663687f : 1.0f;
#pragma unroll
    for (int it = 0; it < 4; it++) {  // 128x8 slots = 1024
        int idx = tid + it * 256;
        int kk = idx >> 3, c4 = (idx & 7) * 4;
        *(float4*)(&Ls[kk][c4]) = *(const float4*)(L + (size_t)kk * 128 + hh * 32 + c4);
    }
    {
        int r = tid >> 3, c4 = (tid & 7) * 4;
        *(float4*)(&Ss[r][c4]) = *(const float4*)(S + r * 32 + c4);
    }
    __syncthreads();
    int k = tid >> 1, half = tid & 1;
#pragma unroll
    for (int jj = 0; jj < 16; jj++) {
        int j = half * 16 + jj;
        float s = 0.f;
        if (mode == 0) {
#pragma unroll
            for (int o = 0; o < 32; o++) s += Ls[k][o] * Ss[j][o];
        } else {
#pragma unroll
            for (int d = 0; d < 32; d++) s += Ls[k][d] * Ss[d][j];
        }
        Ot[j][k] = (unsigned short)f2bf(s * ps);
    }
    __syncthreads();
    unsigned short* dst = Wf + ((size_t)(l * TNN + t) * 1664 + (mode == 0 ? 128 : 896)) * 128;
#pragma unroll
    for (int it = 0; it < 2; it++) {  // 32x16 slots
        int idx = tid + it * 256;
        int j = idx >> 4, sg = (idx & 15) * 8;
        uint4 pk = *(const uint4*)(&Ot[j][sg]);
        int jg = (hh * 6 + te) * 32 + j;
        *(uint4*)(dst + (size_t)jg * 128 + sg) = pk;
    }
}

// ---------------- MFMA typed GEMM (LDS B; column-split wave mapping) ----------
// Y[node] = A[node] @ WT[type]^T
// Wave w computes all 64 rows x cols [w*32, w*32+32): per k-step 4 A-frag + 2
// B-frag LDS reads feed 8 MFMAs (was 1+8 with row-split -> 1.5x fewer reads).
// AF32: A fp32 (converted during staging). EPI: 0 none, 1 bias+gelu,
// 2 fused skip-blend+LayerNorm (reads/writes hres fp32, writes hbout bf16).
// OMODE (EPI<2): 0 fp32 out, 1 bf16 out, 2 both
template <int K, int NCB, int EPI, int OMODE, int AF32>
__launch_bounds__(256) __global__
void k_gemm(const void* __restrict__ Av, const unsigned short* __restrict__ WT,
            const float* __restrict__ bias, float* __restrict__ Yf,
            unsigned short* __restrict__ Yb, const int* __restrict__ nperm,
            const int* __restrict__ meta, const float* __restrict__ skipv,
            const float* __restrict__ gamma, const float* __restrict__ beta,
            float* __restrict__ hres, unsigned short* __restrict__ hbout) {
    __shared__ __align__(16) char smem[52224];
    unsigned short* Ab = (unsigned short*)smem;            // [64][136] (272B stride)
    unsigned short* Bs = (unsigned short*)(smem + 17408);  // [128][136]
    float* Cb = (float*)(smem + 17408);                    // alias Bs; stride 68 / 132
    const int WIDTH = NCB * 128;
    int row0 = blockIdx.x * 64;
    if (row0 >= meta[4]) return;
    int t = 0;
    while (t < 3 && row0 >= meta[t + 1]) t++;
    const unsigned short* WTt = WT + (size_t)t * WIDTH * K;
    int tid = threadIdx.x;
    int lane = tid & 63, w = tid >> 6;
    int m = lane & 15, q = lane >> 4;

#pragma unroll 1
    for (int cb = 0; cb < NCB; cb++) {
        f32x4 acc[4][2];
#pragma unroll
        for (int rt = 0; rt < 4; rt++)
#pragma unroll
            for (int ct = 0; ct < 2; ct++) acc[rt][ct] = (f32x4){0.f, 0.f, 0.f, 0.f};
#pragma unroll
        for (int kc = 0; kc < K / 128; kc++) {
            __syncthreads();  // prior Cb(=Bs)/Ab readers done
            if (NCB == 1 || cb == 0) {
                if (AF32) {
                    const float* A = (const float*)Av;
#pragma unroll
                    for (int it = 0; it < 8; it++) {  // 64 rows x 32 slots x 4 floats
                        int idx = tid + it * 256;
                        int r = idx >> 5, c4 = (idx & 31) * 4;
                        int node = nperm[row0 + r];
                        float4 v = make_float4(0.f, 0.f, 0.f, 0.f);
                        if (node >= 0)
                            v = *(const float4*)(A + (size_t)node * K + kc * 128 + c4);
                        uint2 pk;
                        pk.x = f2bf(v.x) | (f2bf(v.y) << 16);
                        pk.y = f2bf(v.z) | (f2bf(v.w) << 16);
                        *(uint2*)(Ab + r * 136 + c4) = pk;
                    }
                } else {
                    const unsigned short* A = (const unsigned short*)Av;
#pragma unroll
                    for (int it = 0; it < 4; it++) {  // 64 rows x 16 slots x 8 bf16
                        int idx = tid + it * 256;
                        int r = idx >> 4, sg = idx & 15;
                        int node = nperm[row0 + r];
                        uint4 v = make_uint4(0, 0, 0, 0);
                        if (node >= 0)
                            v = *(const uint4*)(A + (size_t)node * K + kc * 128 + sg * 8);
                        *(uint4*)(Ab + r * 136 + sg * 8) = v;
                    }
                }
            }
#pragma unroll
            for (int it = 0; it < 8; it++) {  // 128 rows x 16 slots
                int idx = tid + it * 256;
                int n = idx >> 4, sg = idx & 15;
                *(uint4*)(Bs + n * 136 + sg * 8) =
                    *(const uint4*)(WTt + (size_t)(cb * 128 + n) * K + kc * 128 + sg * 8);
            }
            __syncthreads();
#pragma unroll
            for (int k0 = 0; k0 < 128; k0 += 32) {
                bf16x8 b0 = *(const bf16x8*)(Bs + (w * 32 + m) * 136 + k0 + q * 8);
                bf16x8 b1 = *(const bf16x8*)(Bs + (w * 32 + 16 + m) * 136 + k0 + q * 8);
#pragma unroll
                for (int rt = 0; rt < 4; rt++) {
                    bf16x8 a = *(const bf16x8*)(Ab + (rt * 16 + m) * 136 + k0 + q * 8);
                    acc[rt][0] = __builtin_amdgcn_mfma_f32_16x16x32_bf16(a, b0, acc[rt][0], 0, 0, 0);
                    acc[rt][1] = __builtin_amdgcn_mfma_f32_16x16x32_bf16(a, b1, acc[rt][1], 0, 0, 0);
                }
            }
        }
        if (EPI == 2) {
            __syncthreads();
#pragma unroll
            for (int rt = 0; rt < 4; rt++)
#pragma unroll
                for (int ct = 0; ct < 2; ct++)
#pragma unroll
                    for (int r = 0; r < 4; r++)
                        Cb[(rt * 16 + q * 4 + r) * 132 + (w * 2 + ct) * 16 + m] = acc[rt][ct][r];
            __syncthreads();
            // fused skip-blend + LayerNorm; tile type t uniform -> alpha scalar
            float alpha = 1.0f / (1.0f + __expf(-skipv[t]));
            int off = lane * 2;
            float2 g2 = *(const float2*)(gamma + off);
            float2 b2 = *(const float2*)(beta + off);
#pragma unroll 1
            for (int it = 0; it < 16; it++) {
                int row = w * 16 + it;
                int node = nperm[row0 + row];
                if (node < 0) continue;
                float ax = Cb[row * 132 + off];
                float ay = Cb[row * 132 + off + 1];
                float2 h2 = *(const float2*)(hres + (size_t)node * 128 + off);
                float ox = ax * alpha + h2.x * (1.f - alpha);
                float oy = ay * alpha + h2.y * (1.f - alpha);
                float s = ox + oy;
#pragma unroll
                for (int mm = 1; mm < 64; mm <<= 1) s += __shfl_xor(s, mm);
                float mu = s * (1.0f / 128.0f);
                float dx = ox - mu, dy = oy - mu;
                float v2 = dx * dx + dy * dy;
#pragma unroll
                for (int mm = 1; mm < 64; mm <<= 1) v2 += __shfl_xor(v2, mm);
                float rs = rsqrtf(v2 * (1.0f / 128.0f) + 1e-5f);
                float vx = dx * rs * g2.x + b2.x;
                float vy = dy * rs * g2.y + b2.y;
                *(float2*)(hres + (size_t)node * 128 + off) = make_float2(vx, vy);
                *(unsigned*)(hbout + (size_t)node * 128 + off) = f2bf(vx) | (f2bf(vy) << 16);
            }
        } else {
            // two 64-col halves through half-width Cb [64][68]; waves {2hf,2hf+1}
            // own the cols of half hf
#pragma unroll 1
            for (int hf = 0; hf < 2; hf++) {
                __syncthreads();  // prior Cb readers done
                if ((w >> 1) == hf) {
#pragma unroll
                    for (int rt = 0; rt < 4; rt++)
#pragma unroll
                        for (int ct = 0; ct < 2; ct++)
#pragma unroll
                            for (int r = 0; r < 4; r++)
                                Cb[(rt * 16 + q * 4 + r) * 68 + (w & 1) * 32 + ct * 16 + m] =
                                    acc[rt][ct][r];
                }
                __syncthreads();
#pragma unroll
                for (int it = 0; it < 4; it++) {  // 64 rows x 16 slots
                    int idx = tid + it * 256;
                    int row = idx >> 4, c4 = (idx & 15) * 4;
                    int node = nperm[row0 + row];
                    if (node < 0) continue;
                    float4 v = *(const float4*)(Cb + row * 68 + c4);
                    if (EPI == 1) {
                        float4 bv = *(const float4*)(bias + t * 128 + hf * 64 + c4);
                        v.x += bv.x; v.y += bv.y; v.z += bv.z; v.w += bv.w;
                        const float is2 = 0.70710678118654752f;
                        v.x = 0.5f * v.x * (1.f + erff(v.x * is2));
                        v.y = 0.5f * v.y * (1.f + erff(v.y * is2));
                        v.z = 0.5f * v.z * (1.f + erff(v.z * is2));
                        v.w = 0.5f * v.w * (1.f + erff(v.w * is2));
                    }
                    int col = cb * 128 + hf * 64 + c4;
                    if (OMODE == 0 || OMODE == 2)
                        *(float4*)(Yf + (size_t)node * WIDTH + col) = v;
                    if (OMODE == 1 || OMODE == 2) {
                        uint2 pk;
                        pk.x = f2bf(v.x) | (f2bf(v.y) << 16);
                        pk.y = f2bf(v.z) | (f2bf(v.w) << 16);
                        *(uint2*)(Yb + (size_t)node * WIDTH + col) = pk;
                    }
                }
            }
        }
    }
}

// ---------------- fused edge pass, 4-edge unrolled, packed (src,etype) ----------------
// kqv[n][1664]: cols 0..127 = k, 128..895 = qhat, 896..1663 = vhat
__global__ void k_edge(const unsigned short* __restrict__ kqv,
                       const int* __restrict__ offs, const unsigned* __restrict__ se,
                       unsigned short* __restrict__ aggb) {
    int lane = threadIdx.x & 63;
    int wid = blockIdx.x * (blockDim.x >> 6) + (threadIdx.x >> 6);
    int nw = gridDim.x * (blockDim.x >> 6);
    int h = lane >> 4;
    int i2 = (lane & 15) * 2;
    int hoff = h * 32 + i2;
    for (int n = wid; n < NN; n += nw) {
        int e0 = offs[n], e1 = offs[n + 1];
        float ax = 0.f, ay = 0.f, den = 0.f;
        const unsigned short* qrow = kqv + (size_t)n * 1664 + 128;
        int s[4], t[4];
#pragma unroll
        for (int u = 0; u < 4; u++) {
            s[u] = 0; t[u] = 0;
            if (e0 + u < e1) { unsigned p0 = se[e0 + u]; s[u] = p0 >> 3; t[u] = p0 & 7; }
        }
        int j = e0;
        while (j + 3 < e1) {
            unsigned ku[4], qu[4], vu[4];
#pragma unroll
            for (int u = 0; u < 4; u++) {
                int to = (h * 6 + t[u]) * 32 + i2;
                ku[u] = *(const unsigned*)(kqv + (size_t)s[u] * 1664 + hoff);
                qu[u] = *(const unsigned*)(qrow + to);
                vu[u] = *(const unsigned*)(kqv + (size_t)s[u] * 1664 + 896 + to);
            }
            int jn = j + 4;
#pragma unroll
            for (int u = 0; u < 4; u++)
                if (jn + u < e1) { unsigned p0 = se[jn + u]; s[u] = p0 >> 3; t[u] = p0 & 7; }
            float p[4];
#pragma unroll
            for (int u = 0; u < 4; u++)
                p[u] = bf_lo(ku[u]) * bf_lo(qu[u]) + bf_hi(ku[u]) * bf_hi(qu[u]);
#pragma unroll
            for (int mm = 1; mm < 16; mm <<= 1) {
#pragma unroll
                for (int u = 0; u < 4; u++) p[u] += __shfl_xor(p[u], mm);
            }
#pragma unroll
            for (int u = 0; u < 4; u++) {
                float ex = __expf(p[u]);
                den += ex;
                ax += ex * bf_lo(vu[u]);
                ay += ex * bf_hi(vu[u]);
            }
            j = jn;
        }
        for (int u = 0; j < e1; j++, u++) {  // tail 0..3 edges
            int to = (h * 6 + t[u]) * 32 + i2;
            unsigned ku = *(const unsigned*)(kqv + (size_t)s[u] * 1664 + hoff);
            unsigned qu = *(const unsigned*)(qrow + to);
            unsigned vu = *(const unsigned*)(kqv + (size_t)s[u] * 1664 + 896 + to);
            float p0 = bf_lo(ku) * bf_lo(qu) + bf_hi(ku) * bf_hi(qu);
            p0 += __shfl_xor(p0, 1);
            p0 += __shfl_xor(p0, 2);
            p0 += __shfl_xor(p0, 4);
            p0 += __shfl_xor(p0, 8);
            float ex = __expf(p0);
            den += ex;
            ax += ex * bf_lo(vu);
            ay += ex * bf_hi(vu);
        }
        float r = (den > 0.f) ? (1.0f / den) : 0.f;
        unsigned pk = f2bf(ax * r) | (f2bf(ay * r) << 16);
        *(unsigned*)(aggb + (size_t)n * 128 + hoff) = pk;
    }
}

// ---------------- output projection (reads bf16 hb) ----------------
__global__ void k_out(const unsigned short* __restrict__ hb, const float* __restrict__ Wo,
                      const float* __restrict__ bo, float* __restrict__ out) {
    __shared__ float Ws[128 * 16];
    int tid = threadIdx.x;
#pragma unroll
    for (int it = 0; it < 2; it++) {
        int idx = (tid + it * 256) * 4;
        *(float4*)(&Ws[idx]) = *(const float4*)(Wo + idx);
    }
    __syncthreads();
    int nl = tid >> 4;
    int o = tid & 15;
    int n = blockIdx.x * 16 + nl;
    float acc = bo[o];
    const unsigned short* hr = hb + (size_t)n * 128;
#pragma unroll
    for (int kk = 0; kk < 128; kk += 8) {
        uint4 hv = *(const uint4*)(hr + kk);
        acc += bf_lo(hv.x) * Ws[(kk + 0) * 16 + o] + bf_hi(hv.x) * Ws[(kk + 1) * 16 + o] +
               bf_lo(hv.y) * Ws[(kk + 2) * 16 + o] + bf_hi(hv.y) * Ws[(kk + 3) * 16 + o] +
               bf_lo(hv.z) * Ws[(kk + 4) * 16 + o] + bf_hi(hv.z) * Ws[(kk + 5) * 16 + o] +
               bf_lo(hv.w) * Ws[(kk + 6) * 16 + o] + bf_hi(hv.w) * Ws[(kk + 7) * 16 + o];
    }
    out[(size_t)n * 16 + o] = acc;
}

extern "C" void kernel_launch(void* const* d_in, const int* in_sizes, int n_in,
                              void* d_out, int out_size, void* d_ws, size_t ws_size,
                              hipStream_t stream) {
    const float* x       = (const float*)d_in[0];
    const float* adapt_W = (const float*)d_in[1];
    const float* adapt_b = (const float*)d_in[2];
    const float* Wk      = (const float*)d_in[3];
    const float* Wq      = (const float*)d_in[4];
    const float* Wv      = (const float*)d_in[5];
    const float* pri     = (const float*)d_in[6];
    const float* Wa      = (const float*)d_in[7];
    const float* Wm      = (const float*)d_in[8];
    const float* Wla     = (const float*)d_in[9];
    const float* skip    = (const float*)d_in[10];
    const float* gamma   = (const float*)d_in[11];
    const float* beta    = (const float*)d_in[12];
    const float* out_W   = (const float*)d_in[13];
    const float* out_b   = (const float*)d_in[14];
    const int* ntype     = (const int*)d_in[15];
    const int* etype     = (const int*)d_in[16];
    const int* src       = (const int*)d_in[17];
    const int* dst       = (const int*)d_in[18];
    float* out = (float*)d_out;

    char* p = (char*)d_ws;
    auto al = [](size_t v) { return (v + 255) & ~(size_t)255; };
    float* h  = (float*)p;          p += al((size_t)NN * 128 * 4);
    unsigned short* hb   = (unsigned short*)p; p += al((size_t)NN * 128 * 2);
    unsigned short* aggb = (unsigned short*)p; p += al((size_t)NN * 128 * 2);
    unsigned short* kqvb = (unsigned short*)p; p += al((size_t)NN * 1664 * 2);
    unsigned short* adaptT = (unsigned short*)p; p += al((size_t)TNN * 128 * 256 * 2);
    unsigned short* WlaT   = (unsigned short*)p; p += al((size_t)LLL * TNN * 16384 * 2);
    unsigned short* Wf     = (unsigned short*)p; p += al((size_t)LLL * TNN * 1664 * 128 * 2);
    int* deg   = (int*)p; p += al((size_t)NN * 4);
    int* offs  = (int*)p; p += al((size_t)(NN + 1) * 4);
    int* cur   = (int*)p; p += al((size_t)NN * 4);
    unsigned* se = (unsigned*)p; p += al((size_t)EE * 4);
    int* nperm = (int*)p; p += al((size_t)(NN + 512) * 4);
    int* bsum  = (int*)p; p += al(256 * 4);
    int* bpre  = (int*)p; p += al(256 * 4);
    int* ncnt  = (int*)p; p += al(64);
    int* ncur  = (int*)p; p += al(64);
    int* meta  = (int*)p; p += al(64);

    k_init<<<(NN + 512 + 255) / 256, 256, 0, stream>>>(deg, cur, ncnt, ncur, nperm);
    k_count_edges<<<(EE + 255) / 256, 256, 0, stream>>>(dst, deg);
    k_count_types<<<(NN + 255) / 256, 256, 0, stream>>>(ntype, ncnt);
    k_scan1<<<NB, 256, 0, stream>>>(deg, bsum);
    k_scan2<<<1, 256, 0, stream>>>(bsum, bpre, ncnt, meta);
    k_scan3<<<NB, 256, 0, stream>>>(deg, bpre, offs);
    k_scatter_edges<<<(EE + 255) / 256, 256, 0, stream>>>(dst, src, etype, offs, cur, se);
    k_scatter_nodes<<<(NN + 255) / 256, 256, 0, stream>>>(ntype, meta, ncur, nperm);

    k_wt<<<96, 256, 0, stream>>>(adapt_W, Wk, Wla, adaptT, Wf, WlaT);
    k_comb<<<384, 256, 0, stream>>>(Wq, Wa, Wv, Wm, pri, Wf);

    const int TILES = NN / 64 + TNN + 1;

    // adapt: h = gelu(x @ adaptT + b) with on-the-fly fp32->bf16 A-staging
    k_gemm<256, 1, 1, 2, 1><<<TILES, 256, 0, stream>>>(
        x, adaptT, adapt_b, h, hb, nperm, meta, nullptr, nullptr, nullptr, nullptr, nullptr);

    for (int l = 0; l < LLL; l++) {
        // fused K|Q|V: kqv[n][1664] in one MFMA GEMM
        k_gemm<128, 13, 0, 1, 0><<<TILES, 256, 0, stream>>>(
            hb, Wf + (size_t)l * TNN * 1664 * 128, nullptr, nullptr, kqvb, nperm, meta,
            nullptr, nullptr, nullptr, nullptr, nullptr);

        k_edge<<<4096, 256, 0, stream>>>(kqvb, offs, se, aggb);

        // Wla GEMM + fused skip-blend + LayerNorm (updates h fp32 and hb bf16)
        k_gemm<128, 1, 2, 0, 0><<<TILES, 256, 0, stream>>>(
            aggb, WlaT + (size_t)l * TNN * 16384, nullptr, nullptr, nullptr, nperm, meta,
            skip + (size_t)l * TNN, gamma + (size_t)l * HIDD, beta + (size_t)l * HIDD,
            h, hb);
    }

    k_out<<<NN / 16, 256, 0, stream>>>(hb, out_W, out_b, out);
}

// Round 12
// 608.969 us; speedup vs baseline: 1.5368x; 1.0662x over previous
//
#include <hip/hip_runtime.h>
#include <hip/hip_bf16.h>
#include <math.h>

#define NN   50000
#define EE   400000
#define NINP 256
#define HH   4
#define DD   32
#define HIDD 128
#define TNN  4
#define TEE  6
#define LLL  2
#define NOUTT 16
#define NB   196   // (NN+255)/256 scan blocks

// RULE: every LDS array row stride must be a multiple of 4 fp32 / 8 bf16
// elements so vector b128 accesses stay 16B-aligned (2 crashed rounds).
// RULE: every LDS staging loop must cover rows*cols/threads slots (round 6).
// RULE (round 10): don't feed MFMA straight from global — L2 latency stalls the
// pipe. (round 11): reshuffling wave->tile mapping doesn't cut LDS bytes; hold
// the k-invariant operand (A) in REGISTERS and keep only B in LDS.

typedef __attribute__((ext_vector_type(8))) short bf16x8;
typedef __attribute__((ext_vector_type(4))) float f32x4;

__device__ __forceinline__ float bf_lo(unsigned u) { return __uint_as_float(u << 16); }
__device__ __forceinline__ float bf_hi(unsigned u) { return __uint_as_float(u & 0xFFFF0000u); }
__device__ __forceinline__ unsigned f2bf(float f) {
    unsigned u = __float_as_uint(f);
    u += 0x7FFFu + ((u >> 16) & 1u);
    return (u >> 16);
}

// ---------------- workspace init ----------------
__global__ void k_init(int* __restrict__ deg, int* __restrict__ cur, int* __restrict__ ncnt,
                       int* __restrict__ ncur, int* __restrict__ nperm) {
    int i = blockIdx.x * 256 + threadIdx.x;
    if (i < NN) { deg[i] = 0; cur[i] = 0; }
    if (i < 16) { ncnt[i] = 0; ncur[i] = 0; }
    if (i < NN + 512) nperm[i] = -1;
}

// ---------------- CSR / sort build ----------------
__global__ void k_count_edges(const int* __restrict__ dst, int* __restrict__ deg) {
    int e = blockIdx.x * 256 + threadIdx.x;
    if (e < EE) atomicAdd(&deg[dst[e]], 1);
}
__global__ void k_count_types(const int* __restrict__ ntype, int* __restrict__ ncnt) {
    int n = blockIdx.x * 256 + threadIdx.x;
    int lane = threadIdx.x & 63;
    int t = (n < NN) ? ntype[n] : -1;
#pragma unroll
    for (int tt = 0; tt < TNN; tt++) {
        unsigned long long mask = __ballot(t == tt);
        if (mask && lane == (__ffsll((unsigned long long)mask) - 1))
            atomicAdd(&ncnt[tt], __popcll(mask));
    }
}
// 3-pass scan
__global__ void k_scan1(const int* __restrict__ deg, int* __restrict__ bsum) {
    int i = blockIdx.x * 256 + threadIdx.x;
    int lane = threadIdx.x & 63, wv = threadIdx.x >> 6;
    __shared__ int ws[4];
    int x = (i < NN) ? deg[i] : 0;
#pragma unroll
    for (int off = 1; off < 64; off <<= 1) x += __shfl_xor(x, off);
    if (lane == 0) ws[wv] = x;
    __syncthreads();
    if (threadIdx.x == 0) bsum[blockIdx.x] = ws[0] + ws[1] + ws[2] + ws[3];
}
__global__ void k_scan2(const int* __restrict__ bsum, int* __restrict__ bpre,
                        const int* __restrict__ ncnt, int* __restrict__ meta) {
    __shared__ int ws[4];
    int tid = threadIdx.x, lane = tid & 63, wv = tid >> 6;
    int v = (tid < NB) ? bsum[tid] : 0;
    int x = v;
#pragma unroll
    for (int off = 1; off < 64; off <<= 1) {
        int y = __shfl_up(x, off);
        if (lane >= off) x += y;
    }
    if (lane == 63) ws[wv] = x;
    __syncthreads();
    if (tid == 0) { int a = 0; for (int w = 0; w < 4; w++) { int s = ws[w]; ws[w] = a; a += s; } }
    __syncthreads();
    if (tid < NB) bpre[tid] = x - v + ws[wv];
    if (tid == 0) {
        int acc = 0;
        meta[0] = 0;
        for (int t = 0; t < TNN; t++) { acc += ((ncnt[t] + 63) >> 6) << 6; meta[t + 1] = acc; }
    }
}
__global__ void k_scan3(const int* __restrict__ deg, const int* __restrict__ bpre,
                        int* __restrict__ offs) {
    int b = blockIdx.x;
    int tid = threadIdx.x, lane = tid & 63, wv = tid >> 6;
    int i = b * 256 + tid;
    __shared__ int ws[4];
    int v = (i < NN) ? deg[i] : 0;
    int x = v;
#pragma unroll
    for (int off = 1; off < 64; off <<= 1) {
        int y = __shfl_up(x, off);
        if (lane >= off) x += y;
    }
    if (lane == 63) ws[wv] = x;
    __syncthreads();
    if (tid == 0) { int a = 0; for (int w = 0; w < 4; w++) { int s = ws[w]; ws[w] = a; a += s; } }
    __syncthreads();
    if (i < NN) offs[i + 1] = x + ws[wv] + bpre[b];
    if (b == 0 && tid == 0) offs[0] = 0;
}
// writes packed (src<<3)|etype per CSR slot
__global__ void k_scatter_edges(const int* __restrict__ dst, const int* __restrict__ src,
                                const int* __restrict__ etype, const int* __restrict__ offs,
                                int* __restrict__ cur, unsigned* __restrict__ se) {
    int e = blockIdx.x * 256 + threadIdx.x;
    if (e < EE) {
        int d = dst[e];
        int p = atomicAdd(&cur[d], 1);
        se[offs[d] + p] = ((unsigned)src[e] << 3) | (unsigned)etype[e];
    }
}
__global__ void k_scatter_nodes(const int* __restrict__ ntype, const int* __restrict__ meta,
                                int* __restrict__ ncur, int* __restrict__ nperm) {
    int n = blockIdx.x * 256 + threadIdx.x;
    int lane = threadIdx.x & 63;
    int t = (n < NN) ? ntype[n] : -1;
#pragma unroll
    for (int tt = 0; tt < TNN; tt++) {
        unsigned long long mask = __ballot(t == tt);
        if (t == tt) {
            int rank = __popcll(mask & ((1ull << lane) - 1ull));
            int leader = __ffsll((unsigned long long)mask) - 1;
            int b = 0;
            if (rank == 0) b = atomicAdd(&ncur[tt], __popcll(mask));
            b = __shfl(b, leader);
            nperm[meta[tt] + b + rank] = n;
        }
    }
}

// ---------------- weight transpose+convert: W[t][k][n] f32 -> WT[t][n][k] bf16 ----------
__global__ void k_wt(const float* __restrict__ adapt_W, const float* __restrict__ Wk,
                     const float* __restrict__ Wla, unsigned short* __restrict__ adaptT,
                     unsigned short* __restrict__ Wf, unsigned short* __restrict__ WlaT) {
    __shared__ float Ts[64][68];  // 272B row stride
    int b = blockIdx.x, tid = threadIdx.x;
    const float* src;
    unsigned short* dst;
    int K, kt, nt;
    if (b < 32) {
        int t = b >> 3, tile = b & 7;
        K = 256; kt = tile >> 1; nt = tile & 1;
        src = adapt_W + (size_t)t * 256 * 128;
        dst = adaptT + (size_t)t * 128 * 256;
    } else if (b < 64) {
        int b2 = b - 32, l = b2 >> 4, r = b2 & 15, t = r >> 2, tile = r & 3;
        K = 128; kt = tile >> 1; nt = tile & 1;
        src = Wk + (size_t)(l * 4 + t) * 16384;
        dst = Wf + (size_t)(l * TNN + t) * 1664 * 128;  // fused rows 0..127
    } else {
        int b2 = b - 64, l = b2 >> 4, r = b2 & 15, t = r >> 2, tile = r & 3;
        K = 128; kt = tile >> 1; nt = tile & 1;
        src = Wla + (size_t)(l * 4 + t) * 16384;
        dst = WlaT + (size_t)(l * 4 + t) * 16384;
    }
    int k0 = kt * 64, n0 = nt * 64;
#pragma unroll
    for (int it = 0; it < 4; it++) {  // 64x16 slots
        int idx = tid + it * 256;
        int row = idx >> 4, c4 = (idx & 15) * 4;
        *(float4*)(&Ts[row][c4]) = *(const float4*)(src + (size_t)(k0 + row) * 128 + n0 + c4);
    }
    __syncthreads();
#pragma unroll
    for (int it = 0; it < 2; it++) {  // 64x8 slots
        int idx = tid + it * 256;
        int nn = idx >> 3, sg = (idx & 7) * 8;
        uint4 pk;
        pk.x = f2bf(Ts[sg + 0][nn]) | (f2bf(Ts[sg + 1][nn]) << 16);
        pk.y = f2bf(Ts[sg + 2][nn]) | (f2bf(Ts[sg + 3][nn]) << 16);
        pk.z = f2bf(Ts[sg + 4][nn]) | (f2bf(Ts[sg + 5][nn]) << 16);
        pk.w = f2bf(Ts[sg + 6][nn]) | (f2bf(Ts[sg + 7][nn]) << 16);
        *(uint4*)(dst + (size_t)(n0 + nn) * K + k0 + sg) = pk;
    }
}

// ---------------- combined weights into fused buffer ----------------
__global__ void k_comb(const float* __restrict__ Wq, const float* __restrict__ Wa,
                       const float* __restrict__ Wv, const float* __restrict__ Wm,
                       const float* __restrict__ pri, unsigned short* __restrict__ Wf) {
    __shared__ float Ls[128][36];
    __shared__ float Ss[32][36];
    __shared__ unsigned short Ot[32][136];
    int b = blockIdx.x, tid = threadIdx.x;
    int mode = b / 192;
    int rem = b % 192;
    int l = rem / 96;
    int rem2 = rem % 96;
    int t = rem2 / 24;
    int ht = rem2 % 24;
    int hh = ht / 6, te = ht % 6;
    const float* L = (mode == 0 ? Wq : Wv) + ((size_t)(l * TNN + t)) * 16384;
    const float* S = (mode == 0 ? Wa : Wm) + ((size_t)((l * HH + hh) * TEE + te)) * 1024;
    float ps = (mode == 0) ? pri[(l * HH + hh) * TEE + te] * 0.17677669529663687f : 1.0f;
#pragma unroll
    for (int it = 0; it < 4; it++) {  // 128x8 slots = 1024
        int idx = tid + it * 256;
        int kk = idx >> 3, c4 = (idx & 7) * 4;
        *(float4*)(&Ls[kk][c4]) = *(const float4*)(L + (size_t)kk * 128 + hh * 32 + c4);
    }
    {
        int r = tid >> 3, c4 = (tid & 7) * 4;
        *(float4*)(&Ss[r][c4]) = *(const float4*)(S + r * 32 + c4);
    }
    __syncthreads();
    int k = tid >> 1, half = tid & 1;
#pragma unroll
    for (int jj = 0; jj < 16; jj++) {
        int j = half * 16 + jj;
        float s = 0.f;
        if (mode == 0) {
#pragma unroll
            for (int o = 0; o < 32; o++) s += Ls[k][o] * Ss[j][o];
        } else {
#pragma unroll
            for (int d = 0; d < 32; d++) s += Ls[k][d] * Ss[d][j];
        }
        Ot[j][k] = (unsigned short)f2bf(s * ps);
    }
    __syncthreads();
    unsigned short* dst = Wf + ((size_t)(l * TNN + t) * 1664 + (mode == 0 ? 128 : 896)) * 128;
#pragma unroll
    for (int it = 0; it < 2; it++) {  // 32x16 slots
        int idx = tid + it * 256;
        int j = idx >> 4, sg = (idx & 15) * 8;
        uint4 pk = *(const uint4*)(&Ot[j][sg]);
        int jg = (hh * 6 + te) * 32 + j;
        *(uint4*)(dst + (size_t)jg * 128 + sg) = pk;
    }
}

// ---------------- legacy MFMA typed GEMM (kept for adapt: K=256, AF32) ----------
template <int K, int NCB, int EPI, int OMODE, int AF32>
__launch_bounds__(256) __global__
void k_gemm(const void* __restrict__ Av, const unsigned short* __restrict__ WT,
            const float* __restrict__ bias, float* __restrict__ Yf,
            unsigned short* __restrict__ Yb, const int* __restrict__ nperm,
            const int* __restrict__ meta) {
    __shared__ __align__(16) char smem[52224];
    unsigned short* Ab = (unsigned short*)smem;            // [64][136]
    unsigned short* Bs = (unsigned short*)(smem + 17408);  // [128][136]
    float* Cb = (float*)(smem + 17408);                    // alias Bs; stride 68
    const int WIDTH = NCB * 128;
    int row0 = blockIdx.x * 64;
    if (row0 >= meta[4]) return;
    int t = 0;
    while (t < 3 && row0 >= meta[t + 1]) t++;
    const unsigned short* WTt = WT + (size_t)t * WIDTH * K;
    int tid = threadIdx.x;
    int lane = tid & 63, w = tid >> 6;
    int m = lane & 15, q = lane >> 4;

#pragma unroll 1
    for (int cb = 0; cb < NCB; cb++) {
        f32x4 acc[4][2];
#pragma unroll
        for (int rt = 0; rt < 4; rt++)
#pragma unroll
            for (int ct = 0; ct < 2; ct++) acc[rt][ct] = (f32x4){0.f, 0.f, 0.f, 0.f};
#pragma unroll
        for (int kc = 0; kc < K / 128; kc++) {
            __syncthreads();
            if (AF32) {
                const float* A = (const float*)Av;
#pragma unroll
                for (int it = 0; it < 8; it++) {
                    int idx = tid + it * 256;
                    int r = idx >> 5, c4 = (idx & 31) * 4;
                    int node = nperm[row0 + r];
                    float4 v = make_float4(0.f, 0.f, 0.f, 0.f);
                    if (node >= 0)
                        v = *(const float4*)(A + (size_t)node * K + kc * 128 + c4);
                    uint2 pk;
                    pk.x = f2bf(v.x) | (f2bf(v.y) << 16);
                    pk.y = f2bf(v.z) | (f2bf(v.w) << 16);
                    *(uint2*)(Ab + r * 136 + c4) = pk;
                }
            }
#pragma unroll
            for (int it = 0; it < 8; it++) {
                int idx = tid + it * 256;
                int n = idx >> 4, sg = idx & 15;
                *(uint4*)(Bs + n * 136 + sg * 8) =
                    *(const uint4*)(WTt + (size_t)(cb * 128 + n) * K + kc * 128 + sg * 8);
            }
            __syncthreads();
#pragma unroll
            for (int k0 = 0; k0 < 128; k0 += 32) {
                bf16x8 b0 = *(const bf16x8*)(Bs + (w * 32 + m) * 136 + k0 + q * 8);
                bf16x8 b1 = *(const bf16x8*)(Bs + (w * 32 + 16 + m) * 136 + k0 + q * 8);
#pragma unroll
                for (int rt = 0; rt < 4; rt++) {
                    bf16x8 a = *(const bf16x8*)(Ab + (rt * 16 + m) * 136 + k0 + q * 8);
                    acc[rt][0] = __builtin_amdgcn_mfma_f32_16x16x32_bf16(a, b0, acc[rt][0], 0, 0, 0);
                    acc[rt][1] = __builtin_amdgcn_mfma_f32_16x16x32_bf16(a, b1, acc[rt][1], 0, 0, 0);
                }
            }
        }
        // two 64-col halves through half-width Cb [64][68]
#pragma unroll 1
        for (int hf = 0; hf < 2; hf++) {
            __syncthreads();
            if ((w >> 1) == hf) {
#pragma unroll
                for (int rt = 0; rt < 4; rt++)
#pragma unroll
                    for (int ct = 0; ct < 2; ct++)
#pragma unroll
                        for (int r = 0; r < 4; r++)
                            Cb[(rt * 16 + q * 4 + r) * 68 + (w & 1) * 32 + ct * 16 + m] =
                                acc[rt][ct][r];
            }
            __syncthreads();
#pragma unroll
            for (int it = 0; it < 4; it++) {
                int idx = tid + it * 256;
                int row = idx >> 4, c4 = (idx & 15) * 4;
                int node = nperm[row0 + row];
                if (node < 0) continue;
                float4 v = *(const float4*)(Cb + row * 68 + c4);
                if (EPI == 1) {
                    float4 bv = *(const float4*)(bias + t * 128 + hf * 64 + c4);
                    v.x += bv.x; v.y += bv.y; v.z += bv.z; v.w += bv.w;
                    const float is2 = 0.70710678118654752f;
                    v.x = 0.5f * v.x * (1.f + erff(v.x * is2));
                    v.y = 0.5f * v.y * (1.f + erff(v.y * is2));
                    v.z = 0.5f * v.z * (1.f + erff(v.z * is2));
                    v.w = 0.5f * v.w * (1.f + erff(v.w * is2));
                }
                int col = cb * 128 + hf * 64 + c4;
                if (OMODE == 0 || OMODE == 2)
                    *(float4*)(Yf + (size_t)node * WIDTH + col) = v;
                if (OMODE == 1 || OMODE == 2) {
                    uint2 pk;
                    pk.x = f2bf(v.x) | (f2bf(v.y) << 16);
                    pk.y = f2bf(v.z) | (f2bf(v.w) << 16);
                    *(uint2*)(Yb + (size_t)node * WIDTH + col) = pk;
                }
            }
        }
    }
}

// ---------------- K=128 MFMA GEMM, A resident in registers ----------------
// Per wave: 16 A-frags (64 VGPRs) loaded ONCE from global; only B goes
// through LDS (34.8 KB). EPI: 0 -> bf16 out (single-pass bf16 Cb epilogue),
// 2 -> fused skip-blend+LayerNorm (fp32 Cb).
template <int NCB, int EPI>
__launch_bounds__(256) __global__
void k_gemm_reg(const unsigned short* __restrict__ A, const unsigned short* __restrict__ WT,
                unsigned short* __restrict__ Yb, const int* __restrict__ nperm,
                const int* __restrict__ meta, const float* __restrict__ skipv,
                const float* __restrict__ gamma, const float* __restrict__ beta,
                float* __restrict__ hres, unsigned short* __restrict__ hbout) {
    __shared__ __align__(16) char smem[34816];
    unsigned short* Bs = (unsigned short*)smem;     // [128][136] (272B stride)
    unsigned short* Cb16 = (unsigned short*)smem;   // [64][136] bf16 (EPI 0, alias)
    float* Cbf = (float*)smem;                      // [64][132] f32 (EPI 2, alias)
    const int WIDTH = NCB * 128;
    int row0 = blockIdx.x * 64;
    if (row0 >= meta[4]) return;
    int t = 0;
    while (t < 3 && row0 >= meta[t + 1]) t++;
    const unsigned short* WTt = WT + (size_t)t * WIDTH * 128;
    int tid = threadIdx.x;
    int lane = tid & 63, w = tid >> 6;
    int m = lane & 15, q = lane >> 4;

    // A-frags in registers: a[rt][kk] = A[row rt*16+m][kk*32 + q*8 .. +7]
    bf16x8 a[4][4];
#pragma unroll
    for (int rt = 0; rt < 4; rt++) {
        int nd = nperm[row0 + rt * 16 + m];
#pragma unroll
        for (int kk = 0; kk < 4; kk++) {
            if (nd >= 0)
                a[rt][kk] = *(const bf16x8*)(A + (size_t)nd * 128 + kk * 32 + q * 8);
            else
                a[rt][kk] = (bf16x8){0, 0, 0, 0, 0, 0, 0, 0};
        }
    }

#pragma unroll 1
    for (int cb = 0; cb < NCB; cb++) {
        f32x4 acc[4][2];
#pragma unroll
        for (int rt = 0; rt < 4; rt++)
#pragma unroll
            for (int ct = 0; ct < 2; ct++) acc[rt][ct] = (f32x4){0.f, 0.f, 0.f, 0.f};
        __syncthreads();  // prior epilogue's LDS reads done (Bs/Cb alias)
#pragma unroll
        for (int it = 0; it < 8; it++) {  // stage B: 128 rows x 16 slots
            int idx = tid + it * 256;
            int n = idx >> 4, sg = idx & 15;
            *(uint4*)(Bs + n * 136 + sg * 8) =
                *(const uint4*)(WTt + (size_t)(cb * 128 + n) * 128 + sg * 8);
        }
        __syncthreads();
#pragma unroll
        for (int kk = 0; kk < 4; kk++) {
            bf16x8 b0 = *(const bf16x8*)(Bs + (w * 32 + m) * 136 + kk * 32 + q * 8);
            bf16x8 b1 = *(const bf16x8*)(Bs + (w * 32 + 16 + m) * 136 + kk * 32 + q * 8);
#pragma unroll
            for (int rt = 0; rt < 4; rt++) {
                acc[rt][0] = __builtin_amdgcn_mfma_f32_16x16x32_bf16(a[rt][kk], b0, acc[rt][0], 0, 0, 0);
                acc[rt][1] = __builtin_amdgcn_mfma_f32_16x16x32_bf16(a[rt][kk], b1, acc[rt][1], 0, 0, 0);
            }
        }
        __syncthreads();  // B reads done before Cb (alias) write
        if (EPI == 2) {
#pragma unroll
            for (int rt = 0; rt < 4; rt++)
#pragma unroll
                for (int ct = 0; ct < 2; ct++)
#pragma unroll
                    for (int r = 0; r < 4; r++)
                        Cbf[(rt * 16 + q * 4 + r) * 132 + w * 32 + ct * 16 + m] = acc[rt][ct][r];
            __syncthreads();
            // fused skip-blend + LayerNorm; tile type t uniform -> alpha scalar
            float alpha = 1.0f / (1.0f + __expf(-skipv[t]));
            int off = lane * 2;
            float2 g2 = *(const float2*)(gamma + off);
            float2 b2 = *(const float2*)(beta + off);
#pragma unroll 1
            for (int it = 0; it < 16; it++) {
                int row = w * 16 + it;
                int node = nperm[row0 + row];
                if (node < 0) continue;
                float ax = Cbf[row * 132 + off];
                float ay = Cbf[row * 132 + off + 1];
                float2 h2 = *(const float2*)(hres + (size_t)node * 128 + off);
                float ox = ax * alpha + h2.x * (1.f - alpha);
                float oy = ay * alpha + h2.y * (1.f - alpha);
                float s = ox + oy;
#pragma unroll
                for (int mm = 1; mm < 64; mm <<= 1) s += __shfl_xor(s, mm);
                float mu = s * (1.0f / 128.0f);
                float dx = ox - mu, dy = oy - mu;
                float v2 = dx * dx + dy * dy;
#pragma unroll
                for (int mm = 1; mm < 64; mm <<= 1) v2 += __shfl_xor(v2, mm);
                float rs = rsqrtf(v2 * (1.0f / 128.0f) + 1e-5f);
                float vx = dx * rs * g2.x + b2.x;
                float vy = dy * rs * g2.y + b2.y;
                *(float2*)(hres + (size_t)node * 128 + off) = make_float2(vx, vy);
                *(unsigned*)(hbout + (size_t)node * 128 + off) = f2bf(vx) | (f2bf(vy) << 16);
            }
        } else {
            // single-pass bf16 epilogue
#pragma unroll
            for (int rt = 0; rt < 4; rt++)
#pragma unroll
                for (int ct = 0; ct < 2; ct++)
#pragma unroll
                    for (int r = 0; r < 4; r++)
                        Cb16[(rt * 16 + q * 4 + r) * 136 + w * 32 + ct * 16 + m] =
                            (unsigned short)f2bf(acc[rt][ct][r]);
            __syncthreads();
#pragma unroll
            for (int it = 0; it < 4; it++) {  // 64 rows x 16 slots of uint4
                int idx = tid + it * 256;
                int row = idx >> 4, sg = idx & 15;
                int node = nperm[row0 + row];
                if (node < 0) continue;
                *(uint4*)(Yb + (size_t)node * WIDTH + cb * 128 + sg * 8) =
                    *(const uint4*)(Cb16 + row * 136 + sg * 8);
            }
        }
    }
}

// ---------------- fused edge pass, 4-edge unrolled, packed (src,etype) ----------------
// kqv[n][1664]: cols 0..127 = k, 128..895 = qhat, 896..1663 = vhat
__global__ void k_edge(const unsigned short* __restrict__ kqv,
                       const int* __restrict__ offs, const unsigned* __restrict__ se,
                       unsigned short* __restrict__ aggb) {
    int lane = threadIdx.x & 63;
    int wid = blockIdx.x * (blockDim.x >> 6) + (threadIdx.x >> 6);
    int nw = gridDim.x * (blockDim.x >> 6);
    int h = lane >> 4;
    int i2 = (lane & 15) * 2;
    int hoff = h * 32 + i2;
    for (int n = wid; n < NN; n += nw) {
        int e0 = offs[n], e1 = offs[n + 1];
        float ax = 0.f, ay = 0.f, den = 0.f;
        const unsigned short* qrow = kqv + (size_t)n * 1664 + 128;
        int s[4], t[4];
#pragma unroll
        for (int u = 0; u < 4; u++) {
            s[u] = 0; t[u] = 0;
            if (e0 + u < e1) { unsigned p0 = se[e0 + u]; s[u] = p0 >> 3; t[u] = p0 & 7; }
        }
        int j = e0;
        while (j + 3 < e1) {
            unsigned ku[4], qu[4], vu[4];
#pragma unroll
            for (int u = 0; u < 4; u++) {
                int to = (h * 6 + t[u]) * 32 + i2;
                ku[u] = *(const unsigned*)(kqv + (size_t)s[u] * 1664 + hoff);
                qu[u] = *(const unsigned*)(qrow + to);
                vu[u] = *(const unsigned*)(kqv + (size_t)s[u] * 1664 + 896 + to);
            }
            int jn = j + 4;
#pragma unroll
            for (int u = 0; u < 4; u++)
                if (jn + u < e1) { unsigned p0 = se[jn + u]; s[u] = p0 >> 3; t[u] = p0 & 7; }
            float p[4];
#pragma unroll
            for (int u = 0; u < 4; u++)
                p[u] = bf_lo(ku[u]) * bf_lo(qu[u]) + bf_hi(ku[u]) * bf_hi(qu[u]);
#pragma unroll
            for (int mm = 1; mm < 16; mm <<= 1) {
#pragma unroll
                for (int u = 0; u < 4; u++) p[u] += __shfl_xor(p[u], mm);
            }
#pragma unroll
            for (int u = 0; u < 4; u++) {
                float ex = __expf(p[u]);
                den += ex;
                ax += ex * bf_lo(vu[u]);
                ay += ex * bf_hi(vu[u]);
            }
            j = jn;
        }
        for (int u = 0; j < e1; j++, u++) {  // tail 0..3 edges
            int to = (h * 6 + t[u]) * 32 + i2;
            unsigned ku = *(const unsigned*)(kqv + (size_t)s[u] * 1664 + hoff);
            unsigned qu = *(const unsigned*)(qrow + to);
            unsigned vu = *(const unsigned*)(kqv + (size_t)s[u] * 1664 + 896 + to);
            float p0 = bf_lo(ku) * bf_lo(qu) + bf_hi(ku) * bf_hi(qu);
            p0 += __shfl_xor(p0, 1);
            p0 += __shfl_xor(p0, 2);
            p0 += __shfl_xor(p0, 4);
            p0 += __shfl_xor(p0, 8);
            float ex = __expf(p0);
            den += ex;
            ax += ex * bf_lo(vu);
            ay += ex * bf_hi(vu);
        }
        float r = (den > 0.f) ? (1.0f / den) : 0.f;
        unsigned pk = f2bf(ax * r) | (f2bf(ay * r) << 16);
        *(unsigned*)(aggb + (size_t)n * 128 + hoff) = pk;
    }
}

// ---------------- output projection (reads bf16 hb) ----------------
__global__ void k_out(const unsigned short* __restrict__ hb, const float* __restrict__ Wo,
                      const float* __restrict__ bo, float* __restrict__ out) {
    __shared__ float Ws[128 * 16];
    int tid = threadIdx.x;
#pragma unroll
    for (int it = 0; it < 2; it++) {
        int idx = (tid + it * 256) * 4;
        *(float4*)(&Ws[idx]) = *(const float4*)(Wo + idx);
    }
    __syncthreads();
    int nl = tid >> 4;
    int o = tid & 15;
    int n = blockIdx.x * 16 + nl;
    float acc = bo[o];
    const unsigned short* hr = hb + (size_t)n * 128;
#pragma unroll
    for (int kk = 0; kk < 128; kk += 8) {
        uint4 hv = *(const uint4*)(hr + kk);
        acc += bf_lo(hv.x) * Ws[(kk + 0) * 16 + o] + bf_hi(hv.x) * Ws[(kk + 1) * 16 + o] +
               bf_lo(hv.y) * Ws[(kk + 2) * 16 + o] + bf_hi(hv.y) * Ws[(kk + 3) * 16 + o] +
               bf_lo(hv.z) * Ws[(kk + 4) * 16 + o] + bf_hi(hv.z) * Ws[(kk + 5) * 16 + o] +
               bf_lo(hv.w) * Ws[(kk + 6) * 16 + o] + bf_hi(hv.w) * Ws[(kk + 7) * 16 + o];
    }
    out[(size_t)n * 16 + o] = acc;
}

extern "C" void kernel_launch(void* const* d_in, const int* in_sizes, int n_in,
                              void* d_out, int out_size, void* d_ws, size_t ws_size,
                              hipStream_t stream) {
    const float* x       = (const float*)d_in[0];
    const float* adapt_W = (const float*)d_in[1];
    const float* adapt_b = (const float*)d_in[2];
    const float* Wk      = (const float*)d_in[3];
    const float* Wq      = (const float*)d_in[4];
    const float* Wv      = (const float*)d_in[5];
    const float* pri     = (const float*)d_in[6];
    const float* Wa      = (const float*)d_in[7];
    const float* Wm      = (const float*)d_in[8];
    const float* Wla     = (const float*)d_in[9];
    const float* skip    = (const float*)d_in[10];
    const float* gamma   = (const float*)d_in[11];
    const float* beta    = (const float*)d_in[12];
    const float* out_W   = (const float*)d_in[13];
    const float* out_b   = (const float*)d_in[14];
    const int* ntype     = (const int*)d_in[15];
    const int* etype     = (const int*)d_in[16];
    const int* src       = (const int*)d_in[17];
    const int* dst       = (const int*)d_in[18];
    float* out = (float*)d_out;

    char* p = (char*)d_ws;
    auto al = [](size_t v) { return (v + 255) & ~(size_t)255; };
    float* h  = (float*)p;          p += al((size_t)NN * 128 * 4);
    unsigned short* hb   = (unsigned short*)p; p += al((size_t)NN * 128 * 2);
    unsigned short* aggb = (unsigned short*)p; p += al((size_t)NN * 128 * 2);
    unsigned short* kqvb = (unsigned short*)p; p += al((size_t)NN * 1664 * 2);
    unsigned short* adaptT = (unsigned short*)p; p += al((size_t)TNN * 128 * 256 * 2);
    unsigned short* WlaT   = (unsigned short*)p; p += al((size_t)LLL * TNN * 16384 * 2);
    unsigned short* Wf     = (unsigned short*)p; p += al((size_t)LLL * TNN * 1664 * 128 * 2);
    int* deg   = (int*)p; p += al((size_t)NN * 4);
    int* offs  = (int*)p; p += al((size_t)(NN + 1) * 4);
    int* cur   = (int*)p; p += al((size_t)NN * 4);
    unsigned* se = (unsigned*)p; p += al((size_t)EE * 4);
    int* nperm = (int*)p; p += al((size_t)(NN + 512) * 4);
    int* bsum  = (int*)p; p += al(256 * 4);
    int* bpre  = (int*)p; p += al(256 * 4);
    int* ncnt  = (int*)p; p += al(64);
    int* ncur  = (int*)p; p += al(64);
    int* meta  = (int*)p; p += al(64);

    k_init<<<(NN + 512 + 255) / 256, 256, 0, stream>>>(deg, cur, ncnt, ncur, nperm);
    k_count_edges<<<(EE + 255) / 256, 256, 0, stream>>>(dst, deg);
    k_count_types<<<(NN + 255) / 256, 256, 0, stream>>>(ntype, ncnt);
    k_scan1<<<NB, 256, 0, stream>>>(deg, bsum);
    k_scan2<<<1, 256, 0, stream>>>(bsum, bpre, ncnt, meta);
    k_scan3<<<NB, 256, 0, stream>>>(deg, bpre, offs);
    k_scatter_edges<<<(EE + 255) / 256, 256, 0, stream>>>(dst, src, etype, offs, cur, se);
    k_scatter_nodes<<<(NN + 255) / 256, 256, 0, stream>>>(ntype, meta, ncur, nperm);

    k_wt<<<96, 256, 0, stream>>>(adapt_W, Wk, Wla, adaptT, Wf, WlaT);
    k_comb<<<384, 256, 0, stream>>>(Wq, Wa, Wv, Wm, pri, Wf);

    const int TILES = NN / 64 + TNN + 1;

    // adapt: h = gelu(x @ adaptT + b) with on-the-fly fp32->bf16 A-staging
    k_gemm<256, 1, 1, 2, 1><<<TILES, 256, 0, stream>>>(
        x, adaptT, adapt_b, h, hb, nperm, meta);

    for (int l = 0; l < LLL; l++) {
        // fused K|Q|V: kqv[n][1664] in one MFMA GEMM, A resident in registers
        k_gemm_reg<13, 0><<<TILES, 256, 0, stream>>>(
            hb, Wf + (size_t)l * TNN * 1664 * 128, kqvb, nperm, meta,
            nullptr, nullptr, nullptr, nullptr, nullptr);

        k_edge<<<4096, 256, 0, stream>>>(kqvb, offs, se, aggb);

        // Wla GEMM + fused skip-blend + LayerNorm (updates h fp32 and hb bf16)
        k_gemm_reg<1, 2><<<TILES, 256, 0, stream>>>(
            aggb, WlaT + (size_t)l * TNN * 16384, nullptr, nperm, meta,
            skip + (size_t)l * TNN, gamma + (size_t)l * HIDD, beta + (size_t)l * HIDD,
            h, hb);
    }

    k_out<<<NN / 16, 256, 0, stream>>>(hb, out_W, out_b, out);
}